// Round 1
// baseline (2387.812 us; speedup 1.0000x reference)
//
#include <hip/hip_runtime.h>

typedef __bf16 bf16x8 __attribute__((ext_vector_type(8)));
typedef float f32x4 __attribute__((ext_vector_type(4)));

#define N_NODES 50000
#define N_EDGES 800000
#define N_TILES (N_EDGES / 16)
#define BA_OFF 0
#define BV_OFF (N_NODES * 64)

// ---- LDS weight layout (ushort units). K=64 rows padded to 72, K=32 rows to 40
#define OFF_WFOLD 0              // 32 x 40
#define OFF_WCAT  1280           // 64 x 72  [WY000 | WY110]
#define OFF_W011  5888           // 16 x 40
#define OFF_WV    6528           // 16 x 72  [WY101 | WY111]
#define OFF_WM1   7680           // 64 x 72
#define OFF_WM2   12288
#define OFF_WM3   16896
#define W_USHORTS 21504

__device__ __forceinline__ unsigned short f2bf(float x) {
    unsigned u = __float_as_uint(x);
    return (unsigned short)((u + 0x7FFFu + ((u >> 16) & 1u)) >> 16);
}
__device__ __forceinline__ unsigned pack2(float a, float b) {
    return (unsigned)f2bf(a) | ((unsigned)f2bf(b) << 16);
}
__device__ __forceinline__ float bf2f(unsigned short h) {
    return __uint_as_float(((unsigned)h) << 16);
}

// ---------------- node features: La = x_a @ W_L0.T ; Lv = einsum(ndi,cd->nci)
// record per node (bf16): [La(32) | Lvx(32) | Lvy(32) | Lvz(32)]
__global__ __launch_bounds__(256) void node_kernel(
    const float* __restrict__ x_a, const float* __restrict__ x_v,
    const float* __restrict__ W_L0, const float* __restrict__ W_L1,
    unsigned short* __restrict__ rec)
{
    int t = blockIdx.x * 256 + threadIdx.x;
    if (t >= N_NODES * 32) return;
    int n = t >> 5, c = t & 31;
    const float* xa = x_a + (size_t)n * 64;
    const float* w0 = W_L0 + c * 64;
    float accA = 0.f;
#pragma unroll
    for (int k = 0; k < 64; ++k) accA += xa[k] * w0[k];
    const float* xv = x_v + (size_t)n * 48;
    const float* w1 = W_L1 + c * 16;
    float a0 = 0.f, a1 = 0.f, a2 = 0.f;
#pragma unroll
    for (int d = 0; d < 16; ++d) {
        float w = w1[d];
        a0 += xv[d * 3 + 0] * w;
        a1 += xv[d * 3 + 1] * w;
        a2 += xv[d * 3 + 2] * w;
    }
    unsigned short* rp = rec + (size_t)n * 128;
    rp[c]      = f2bf(accA);
    rp[32 + c] = f2bf(a0);
    rp[64 + c] = f2bf(a1);
    rp[96 + c] = f2bf(a2);
}

// ---------------- fused edge kernel: one wave = 16 edges, wave-private LDS
__global__ __launch_bounds__(256, 2) void edge_kernel(
    const float* __restrict__ r_ij, const int* __restrict__ src, const int* __restrict__ dst,
    const float* __restrict__ W_enc, const float* __restrict__ b_enc,
    const float* __restrict__ WY000, const float* __restrict__ WY110,
    const float* __restrict__ WY011, const float* __restrict__ WY101, const float* __restrict__ WY111,
    const float* __restrict__ Wm1, const float* __restrict__ bm1,
    const float* __restrict__ Wm2, const float* __restrict__ bm2,
    const float* __restrict__ Wm3,
    const unsigned short* __restrict__ rec, float* __restrict__ out)
{
    __shared__ __align__(16) unsigned short Wlds[W_USHORTS];
    __shared__ __align__(16) unsigned short Buf[4][4096];
    __shared__ __align__(16) float Bias[160];   // b_enc[0:32], b_m1[32:96], b_m2[96:160]

    const int tid = threadIdx.x;

    // ---- stage weights to LDS (bf16), fold W_enc over duplicated coeffs
    for (int idx = tid; idx < 1024; idx += 256) {
        int c = idx >> 5, k = idx & 31;
        float v;
        if (k < 16) v = W_enc[c * 64 + 2 * k] + W_enc[c * 64 + 2 * k + 1];
        else        v = W_enc[c * 64 + 32 + 2 * (k - 16)] + W_enc[c * 64 + 32 + 2 * (k - 16) + 1];
        Wlds[OFF_WFOLD + c * 40 + k] = f2bf(v);
    }
    for (int idx = tid; idx < 4096; idx += 256) {
        int d = idx >> 6, k = idx & 63;
        float v = (k < 32) ? WY000[d * 32 + k] : WY110[d * 32 + (k - 32)];
        Wlds[OFF_WCAT + d * 72 + k] = f2bf(v);
        Wlds[OFF_WM1 + d * 72 + k] = f2bf(Wm1[d * 64 + k]);
        Wlds[OFF_WM2 + d * 72 + k] = f2bf(Wm2[d * 64 + k]);
        Wlds[OFF_WM3 + d * 72 + k] = f2bf(Wm3[d * 64 + k]);
    }
    for (int idx = tid; idx < 512; idx += 256) {
        int vv = idx >> 5, k = idx & 31;
        Wlds[OFF_W011 + vv * 40 + k] = f2bf(WY011[vv * 32 + k]);
    }
    for (int idx = tid; idx < 1024; idx += 256) {
        int vv = idx >> 6, k = idx & 63;
        float w = (k < 32) ? WY101[vv * 32 + k] : WY111[vv * 32 + (k - 32)];
        Wlds[OFF_WV + vv * 72 + k] = f2bf(w);
    }
    if (tid < 32) Bias[tid] = b_enc[tid];
    if (tid < 64) { Bias[32 + tid] = bm1[tid]; Bias[96 + tid] = bm2[tid]; }
    __syncthreads();

    const int wid  = tid >> 6;
    const int lane = tid & 63;
    const int col  = lane & 15;   // edge-in-tile (MFMA n / A-row m)
    const int quad = lane >> 4;   // K-group / C-row group

    unsigned short* yrad = &Buf[wid][0];     // 16 x 40
    unsigned short* ya   = &Buf[wid][640];   // 16 x 72   [y000 | y110]
    unsigned short* yv   = &Buf[wid][1792];  // 16 x 72   [y101_i | y111_i]
    unsigned short* hb   = &Buf[wid][2944];  // 16 x 72   MLP activations

    const f32x4 zero = {0.f, 0.f, 0.f, 0.f};
    float* __restrict__ outA = out + BA_OFF;
    float* __restrict__ outV = out + BV_OFF;

    for (int t = blockIdx.x * 4 + wid; t < N_TILES; t += gridDim.x * 4) {
        const int eg = t * 16 + col;

        // ---- per-edge geometry (each lane redundantly for its col)
        float r0 = r_ij[eg * 3 + 0], r1 = r_ij[eg * 3 + 1], r2 = r_ij[eg * 3 + 2];
        float u  = sqrtf(r0 * r0 + r1 * r1 + r2 * r2);
        float a  = 0.6283185307f * u;          // (pi/5) * dist
        float s14 = 1.4f * u;
        float th  = tanhf(s14);
        float f   = th / fmaxf(s14, 1e-12f);
        float rh0 = 1.4f * r0 * f, rh1 = 1.4f * r1 * f, rh2 = 1.4f * r2 * f;

        // ---- radial features rad[k]: k<16 cos((k+1)a), k>=16 sin((k-15)a)
        float c1, s1;
        __sincosf(a, &s1, &c1);
        // use precise versions to be safe:
        c1 = cosf(a); s1 = sinf(a);
        float cc = c1, ss = s1;
        if (quad & 1) {
#pragma unroll
            for (int m = 0; m < 8; ++m) { float cn = cc * c1 - ss * s1; ss = ss * c1 + cc * s1; cc = cn; }
        }
        unsigned short rv[8];
        bool usec = (quad < 2);
#pragma unroll
        for (int j = 0; j < 8; ++j) {
            rv[j] = f2bf(usec ? cc : ss);
            float cn = cc * c1 - ss * s1; ss = ss * c1 + cc * s1; cc = cn;
        }
        uint4 pk;
        pk.x = (unsigned)rv[0] | ((unsigned)rv[1] << 16);
        pk.y = (unsigned)rv[2] | ((unsigned)rv[3] << 16);
        pk.z = (unsigned)rv[4] | ((unsigned)rv[5] << 16);
        pk.w = (unsigned)rv[6] | ((unsigned)rv[7] << 16);
        *(uint4*)&yrad[col * 40 + quad * 8] = pk;

        // ---- phi GEMM: phi(32 x 16e) = Wfold(32x32) @ rad(32 x 16e)
        bf16x8 brad = *(const bf16x8*)&yrad[col * 40 + quad * 8];
        float phi[2][4];
#pragma unroll
        for (int mt = 0; mt < 2; ++mt) {
            bf16x8 aw = *(const bf16x8*)&Wlds[OFF_WFOLD + (mt * 16 + col) * 40 + quad * 8];
            f32x4 pa = __builtin_amdgcn_mfma_f32_16x16x32_bf16(aw, brad, zero, 0, 0, 0);
#pragma unroll
            for (int r = 0; r < 4; ++r) phi[mt][r] = pa[r] + Bias[mt * 16 + quad * 4 + r];
        }

        // ---- gather node features at dst (bf16 records)
        int nd = dst[eg];
        const unsigned short* rp = rec + (size_t)nd * 128;
        float la[2][4], lv[3][2][4];
#pragma unroll
        for (int mt = 0; mt < 2; ++mt) {
            ushort4 q = *(const ushort4*)&rp[mt * 16 + quad * 4];
            la[mt][0] = bf2f(q.x); la[mt][1] = bf2f(q.y); la[mt][2] = bf2f(q.z); la[mt][3] = bf2f(q.w);
#pragma unroll
            for (int i = 0; i < 3; ++i) {
                ushort4 p = *(const ushort4*)&rp[32 + i * 32 + mt * 16 + quad * 4];
                lv[i][mt][0] = bf2f(p.x); lv[i][mt][1] = bf2f(p.y); lv[i][mt][2] = bf2f(p.z); lv[i][mt][3] = bf2f(p.w);
            }
        }

        // ---- order-0 tensor products -> YA = [y000 | y110] (16e x 64k)
#pragma unroll
        for (int mt = 0; mt < 2; ++mt) {
            float y0[4], y1[4];
#pragma unroll
            for (int r = 0; r < 4; ++r) {
                float dotv = lv[0][mt][r] * rh0 + lv[1][mt][r] * rh1 + lv[2][mt][r] * rh2;
                y0[r] = la[mt][r] * phi[mt][r];
                y1[r] = phi[mt][r] * dotv;
            }
            uint2 w0; w0.x = pack2(y0[0], y0[1]); w0.y = pack2(y0[2], y0[3]);
            *(uint2*)&ya[col * 72 + mt * 16 + quad * 4] = w0;
            uint2 w1; w1.x = pack2(y1[0], y1[1]); w1.y = pack2(y1[2], y1[3]);
            *(uint2*)&ya[col * 72 + 32 + mt * 16 + quad * 4] = w1;
        }

        // ---- psi_a = [y000|y110] @ [WY000|WY110].T   (64 out)
        f32x4 pacc[4] = {zero, zero, zero, zero};
#pragma unroll
        for (int ks = 0; ks < 2; ++ks) {
            bf16x8 bb = *(const bf16x8*)&ya[col * 72 + ks * 32 + quad * 8];
#pragma unroll
            for (int mt = 0; mt < 4; ++mt) {
                bf16x8 aa = *(const bf16x8*)&Wlds[OFF_WCAT + (mt * 16 + col) * 72 + ks * 32 + quad * 8];
                pacc[mt] = __builtin_amdgcn_mfma_f32_16x16x32_bf16(aa, bb, pacc[mt], 0, 0, 0);
            }
        }
        float psi[4][4];
#pragma unroll
        for (int mt = 0; mt < 4; ++mt)
#pragma unroll
            for (int r = 0; r < 4; ++r) psi[mt][r] = pacc[mt][r];

        // ---- t011 = y000 @ WY011.T (16 out, K=32)
        bf16x8 b0 = *(const bf16x8*)&ya[col * 72 + quad * 8];
        bf16x8 a011 = *(const bf16x8*)&Wlds[OFF_W011 + col * 40 + quad * 8];
        f32x4 t011v = __builtin_amdgcn_mfma_f32_16x16x32_bf16(a011, b0, zero, 0, 0, 0);

        // ---- psi_v per component: [y101_i|y111_i] @ [WY101|WY111].T + t011*rh_i
        int sn = src[eg];
        float* __restrict__ ov = outV + (size_t)sn * 48;
#pragma unroll
        for (int i = 0; i < 3; ++i) {
#pragma unroll
            for (int mt = 0; mt < 2; ++mt) {
                float q1[4], q2[4];
#pragma unroll
                for (int r = 0; r < 4; ++r) {
                    q1[r] = phi[mt][r] * lv[i][mt][r];
                    float cr;
                    if (i == 0)      cr = lv[1][mt][r] * rh2 - lv[2][mt][r] * rh1;
                    else if (i == 1) cr = lv[2][mt][r] * rh0 - lv[0][mt][r] * rh2;
                    else             cr = lv[0][mt][r] * rh1 - lv[1][mt][r] * rh0;
                    q2[r] = phi[mt][r] * cr;
                }
                uint2 wa; wa.x = pack2(q1[0], q1[1]); wa.y = pack2(q1[2], q1[3]);
                *(uint2*)&yv[col * 72 + mt * 16 + quad * 4] = wa;
                uint2 wb; wb.x = pack2(q2[0], q2[1]); wb.y = pack2(q2[2], q2[3]);
                *(uint2*)&yv[col * 72 + 32 + mt * 16 + quad * 4] = wb;
            }
            f32x4 vacc = zero;
#pragma unroll
            for (int ks = 0; ks < 2; ++ks) {
                bf16x8 bb = *(const bf16x8*)&yv[col * 72 + ks * 32 + quad * 8];
                bf16x8 aa = *(const bf16x8*)&Wlds[OFF_WV + col * 72 + ks * 32 + quad * 8];
                vacc = __builtin_amdgcn_mfma_f32_16x16x32_bf16(aa, bb, vacc, 0, 0, 0);
            }
            float rhi = (i == 0) ? rh0 : (i == 1) ? rh1 : rh2;
#pragma unroll
            for (int r = 0; r < 4; ++r) {
                float val = 0.1f * (vacc[r] + t011v[r] * rhi);
                atomicAdd(&ov[(quad * 4 + r) * 3 + i], val);
            }
        }

        // ---- residual MLP on psi_a (3x 64x64 GEMM, leaky_relu 0.1)
#pragma unroll
        for (int mt = 0; mt < 4; ++mt) {
            uint2 w; w.x = pack2(psi[mt][0], psi[mt][1]); w.y = pack2(psi[mt][2], psi[mt][3]);
            *(uint2*)&hb[col * 72 + mt * 16 + quad * 4] = w;
        }
        // layer 1
        f32x4 hacc[4] = {zero, zero, zero, zero};
#pragma unroll
        for (int ks = 0; ks < 2; ++ks) {
            bf16x8 bb = *(const bf16x8*)&hb[col * 72 + ks * 32 + quad * 8];
#pragma unroll
            for (int mt = 0; mt < 4; ++mt) {
                bf16x8 aa = *(const bf16x8*)&Wlds[OFF_WM1 + (mt * 16 + col) * 72 + ks * 32 + quad * 8];
                hacc[mt] = __builtin_amdgcn_mfma_f32_16x16x32_bf16(aa, bb, hacc[mt], 0, 0, 0);
            }
        }
#pragma unroll
        for (int mt = 0; mt < 4; ++mt) {
            float h[4];
#pragma unroll
            for (int r = 0; r < 4; ++r) {
                float x = hacc[mt][r] + Bias[32 + mt * 16 + quad * 4 + r];
                h[r] = fmaxf(x, 0.1f * x);
            }
            uint2 w; w.x = pack2(h[0], h[1]); w.y = pack2(h[2], h[3]);
            *(uint2*)&hb[col * 72 + mt * 16 + quad * 4] = w;
        }
        // layer 2
        f32x4 gacc[4] = {zero, zero, zero, zero};
#pragma unroll
        for (int ks = 0; ks < 2; ++ks) {
            bf16x8 bb = *(const bf16x8*)&hb[col * 72 + ks * 32 + quad * 8];
#pragma unroll
            for (int mt = 0; mt < 4; ++mt) {
                bf16x8 aa = *(const bf16x8*)&Wlds[OFF_WM2 + (mt * 16 + col) * 72 + ks * 32 + quad * 8];
                gacc[mt] = __builtin_amdgcn_mfma_f32_16x16x32_bf16(aa, bb, gacc[mt], 0, 0, 0);
            }
        }
#pragma unroll
        for (int mt = 0; mt < 4; ++mt) {
            float h[4];
#pragma unroll
            for (int r = 0; r < 4; ++r) {
                float x = gacc[mt][r] + Bias[96 + mt * 16 + quad * 4 + r];
                h[r] = fmaxf(x, 0.1f * x);
            }
            uint2 w; w.x = pack2(h[0], h[1]); w.y = pack2(h[2], h[3]);
            *(uint2*)&hb[col * 72 + mt * 16 + quad * 4] = w;
        }
        // layer 3 (no bias) + residual + scale + scatter
        f32x4 oacc[4] = {zero, zero, zero, zero};
#pragma unroll
        for (int ks = 0; ks < 2; ++ks) {
            bf16x8 bb = *(const bf16x8*)&hb[col * 72 + ks * 32 + quad * 8];
#pragma unroll
            for (int mt = 0; mt < 4; ++mt) {
                bf16x8 aa = *(const bf16x8*)&Wlds[OFF_WM3 + (mt * 16 + col) * 72 + ks * 32 + quad * 8];
                oacc[mt] = __builtin_amdgcn_mfma_f32_16x16x32_bf16(aa, bb, oacc[mt], 0, 0, 0);
            }
        }
        float* __restrict__ oa = outA + (size_t)sn * 64;
#pragma unroll
        for (int mt = 0; mt < 4; ++mt)
#pragma unroll
            for (int r = 0; r < 4; ++r) {
                float val = 0.1f * (psi[mt][r] + oacc[mt][r]);
                atomicAdd(&oa[mt * 16 + quad * 4 + r], val);
            }
    }
}

extern "C" void kernel_launch(void* const* d_in, const int* in_sizes, int n_in,
                              void* d_out, int out_size, void* d_ws, size_t ws_size,
                              hipStream_t stream) {
    const float* r_ij  = (const float*)d_in[0];
    const float* x_a   = (const float*)d_in[1];
    const float* x_v   = (const float*)d_in[2];
    const int*   src   = (const int*)d_in[3];
    const int*   dst   = (const int*)d_in[4];
    const float* W_L0  = (const float*)d_in[5];
    const float* W_L1  = (const float*)d_in[6];
    const float* W_enc = (const float*)d_in[7];
    const float* b_enc = (const float*)d_in[8];
    const float* WY000 = (const float*)d_in[9];
    const float* WY110 = (const float*)d_in[10];
    const float* WY011 = (const float*)d_in[11];
    const float* WY101 = (const float*)d_in[12];
    const float* WY111 = (const float*)d_in[13];
    const float* Wm1   = (const float*)d_in[14];
    const float* bm1   = (const float*)d_in[15];
    const float* Wm2   = (const float*)d_in[16];
    const float* bm2   = (const float*)d_in[17];
    const float* Wm3   = (const float*)d_in[18];
    float* out = (float*)d_out;
    unsigned short* rec = (unsigned short*)d_ws;   // N_NODES*128 bf16 = 12.8 MB

    hipMemsetAsync(d_out, 0, (size_t)out_size * sizeof(float), stream);
    node_kernel<<<(N_NODES * 32) / 256, 256, 0, stream>>>(x_a, x_v, W_L0, W_L1, rec);
    edge_kernel<<<2048, 256, 0, stream>>>(r_ij, src, dst, W_enc, b_enc,
                                          WY000, WY110, WY011, WY101, WY111,
                                          Wm1, bm1, Wm2, bm2, Wm3, rec, out);
}

// Round 3
// 654.041 us; speedup vs baseline: 3.6509x; 3.6509x over previous
//
#include <hip/hip_runtime.h>

typedef __bf16 bf16x8 __attribute__((ext_vector_type(8)));
typedef float f32x4 __attribute__((ext_vector_type(4)));

#define N_NODES 50000
#define N_EDGES 800000
#define MAXDEG 128
#define BA_OFF 0
#define BV_OFF (N_NODES * 64)

// ---- workspace layout (byte offsets)
#define REC_OFF   0ull            // 50000*128 bf16 = 12.8 MB node records
#define CNT_OFF   12800000ull     // 50000 int degree counts
#define ELL_OFF   13000192ull     // 50000*128 int edge ids = 25.6 MB

// ---- LDS weight layout (ushort units). K=64 rows padded to 72, K=32 rows to 40
#define OFF_WFOLD 0              // 32 x 40
#define OFF_WCAT  1280           // 64 x 72  [WY000 | WY110]
#define OFF_W011  5888           // 16 x 40
#define OFF_WV    6528           // 16 x 72  [WY101 | WY111]
#define OFF_WM1   7680           // 64 x 72
#define OFF_WM2   12288
#define OFF_WM3   16896
#define W_USHORTS 21504

__device__ __forceinline__ unsigned short f2bf(float x) {
    unsigned u = __float_as_uint(x);
    return (unsigned short)((u + 0x7FFFu + ((u >> 16) & 1u)) >> 16);
}
__device__ __forceinline__ unsigned pack2(float a, float b) {
    return (unsigned)f2bf(a) | ((unsigned)f2bf(b) << 16);
}
__device__ __forceinline__ float bf2f(unsigned short h) {
    return __uint_as_float(((unsigned)h) << 16);
}

// ---------------- node features: La = x_a @ W_L0.T ; Lv = einsum(ndi,cd->nci)
// record per node (bf16): [La(32) | Lvx(32) | Lvy(32) | Lvz(32)]
__global__ __launch_bounds__(256) void node_kernel(
    const float* __restrict__ x_a, const float* __restrict__ x_v,
    const float* __restrict__ W_L0, const float* __restrict__ W_L1,
    unsigned short* __restrict__ rec)
{
    int t = blockIdx.x * 256 + threadIdx.x;
    if (t >= N_NODES * 32) return;
    int n = t >> 5, c = t & 31;
    const float* xa = x_a + (size_t)n * 64;
    const float* w0 = W_L0 + c * 64;
    float accA = 0.f;
#pragma unroll
    for (int k = 0; k < 64; ++k) accA += xa[k] * w0[k];
    const float* xv = x_v + (size_t)n * 48;
    const float* w1 = W_L1 + c * 16;
    float a0 = 0.f, a1 = 0.f, a2 = 0.f;
#pragma unroll
    for (int d = 0; d < 16; ++d) {
        float w = w1[d];
        a0 += xv[d * 3 + 0] * w;
        a1 += xv[d * 3 + 1] * w;
        a2 += xv[d * 3 + 2] * w;
    }
    unsigned short* rp = rec + (size_t)n * 128;
    rp[c]      = f2bf(accA);
    rp[32 + c] = f2bf(a0);
    rp[64 + c] = f2bf(a1);
    rp[96 + c] = f2bf(a2);
}

// ---------------- ELL build: bump-allocate each edge into its src node's list
__global__ __launch_bounds__(256) void ell_kernel(
    const int* __restrict__ src, int* __restrict__ cnt, int* __restrict__ ell)
{
    int e = blockIdx.x * 256 + threadIdx.x;
    if (e >= N_EDGES) return;
    int s = src[e];
    int o = atomicAdd(&cnt[s], 1);
    if (o < MAXDEG) ell[(size_t)s * MAXDEG + o] = e;
}

// ---------------- node-major fused kernel: one wave = one node, 16 edges/tile
__global__ __launch_bounds__(256, 2) void node_major_kernel(
    const float* __restrict__ r_ij, const int* __restrict__ dst,
    const float* __restrict__ W_enc, const float* __restrict__ b_enc,
    const float* __restrict__ WY000, const float* __restrict__ WY110,
    const float* __restrict__ WY011, const float* __restrict__ WY101, const float* __restrict__ WY111,
    const float* __restrict__ Wm1, const float* __restrict__ bm1,
    const float* __restrict__ Wm2, const float* __restrict__ bm2,
    const float* __restrict__ Wm3,
    const unsigned short* __restrict__ rec,
    const int* __restrict__ cnt, const int* __restrict__ ell,
    float* __restrict__ out)
{
    __shared__ __align__(16) unsigned short Wlds[W_USHORTS];
    __shared__ __align__(16) unsigned short Buf[4][4096];
    __shared__ __align__(16) float Bias[160];   // b_enc[0:32], b_m1[32:96], b_m2[96:160]

    const int tid = threadIdx.x;

    // ---- stage weights to LDS (bf16), fold W_enc over duplicated coeffs
    for (int idx = tid; idx < 1024; idx += 256) {
        int c = idx >> 5, k = idx & 31;
        float v;
        if (k < 16) v = W_enc[c * 64 + 2 * k] + W_enc[c * 64 + 2 * k + 1];
        else        v = W_enc[c * 64 + 32 + 2 * (k - 16)] + W_enc[c * 64 + 32 + 2 * (k - 16) + 1];
        Wlds[OFF_WFOLD + c * 40 + k] = f2bf(v);
    }
    for (int idx = tid; idx < 4096; idx += 256) {
        int d = idx >> 6, k = idx & 63;
        float v = (k < 32) ? WY000[d * 32 + k] : WY110[d * 32 + (k - 32)];
        Wlds[OFF_WCAT + d * 72 + k] = f2bf(v);
        Wlds[OFF_WM1 + d * 72 + k] = f2bf(Wm1[d * 64 + k]);
        Wlds[OFF_WM2 + d * 72 + k] = f2bf(Wm2[d * 64 + k]);
        Wlds[OFF_WM3 + d * 72 + k] = f2bf(Wm3[d * 64 + k]);
    }
    for (int idx = tid; idx < 512; idx += 256) {
        int vv = idx >> 5, k = idx & 31;
        Wlds[OFF_W011 + vv * 40 + k] = f2bf(WY011[vv * 32 + k]);
    }
    for (int idx = tid; idx < 1024; idx += 256) {
        int vv = idx >> 6, k = idx & 63;
        float w = (k < 32) ? WY101[vv * 32 + k] : WY111[vv * 32 + (k - 32)];
        Wlds[OFF_WV + vv * 72 + k] = f2bf(w);
    }
    if (tid < 32) Bias[tid] = b_enc[tid];
    if (tid < 64) { Bias[32 + tid] = bm1[tid]; Bias[96 + tid] = bm2[tid]; }
    __syncthreads();

    const int wid  = tid >> 6;
    const int lane = tid & 63;
    const int col  = lane & 15;   // edge-slot-in-tile (MFMA n / A-row m)
    const int quad = lane >> 4;   // K-group / C-row group

    unsigned short* yrad = &Buf[wid][0];     // 16 x 40
    unsigned short* ya   = &Buf[wid][640];   // 16 x 72   [y000 | y110]
    unsigned short* yv   = &Buf[wid][1792];  // 16 x 72   [y101_i | y111_i]
    unsigned short* hb   = &Buf[wid][2944];  // 16 x 72   MLP activations

    const f32x4 zero = {0.f, 0.f, 0.f, 0.f};
    float* __restrict__ outA = out + BA_OFF;
    float* __restrict__ outV = out + BV_OFF;

    for (int n = blockIdx.x * 4 + wid; n < N_NODES; n += gridDim.x * 4) {
        int deg = cnt[n];
        deg = (deg < MAXDEG) ? deg : MAXDEG;
        const int* el = ell + (size_t)n * MAXDEG;

        float accA[4][4];
        float accV[12];
#pragma unroll
        for (int mt = 0; mt < 4; ++mt)
#pragma unroll
            for (int r = 0; r < 4; ++r) accA[mt][r] = 0.f;
#pragma unroll
        for (int j = 0; j < 12; ++j) accV[j] = 0.f;

        for (int j0 = 0; j0 < deg; j0 += 16) {
            const int j = j0 + col;
            const bool valid = (j < deg);
            const int eid = el[valid ? j : (deg - 1)];

            // ---- per-edge geometry (each lane redundantly for its col)
            float r0 = r_ij[eid * 3 + 0], r1 = r_ij[eid * 3 + 1], r2 = r_ij[eid * 3 + 2];
            float u  = sqrtf(r0 * r0 + r1 * r1 + r2 * r2);
            float a  = 0.6283185307f * u;          // (pi/5) * dist
            float s14 = 1.4f * u;
            float th  = tanhf(s14);
            float f   = th / fmaxf(s14, 1e-12f);
            float rh0 = 1.4f * r0 * f, rh1 = 1.4f * r1 * f, rh2 = 1.4f * r2 * f;

            // ---- radial features rad[k]: k<16 cos((k+1)a), k>=16 sin((k-15)a)
            float c1 = cosf(a), s1 = sinf(a);
            float cc = c1, ss = s1;
            if (quad & 1) {
#pragma unroll
                for (int m = 0; m < 8; ++m) { float cn = cc * c1 - ss * s1; ss = ss * c1 + cc * s1; cc = cn; }
            }
            unsigned short rv[8];
            bool usec = (quad < 2);
#pragma unroll
            for (int jj = 0; jj < 8; ++jj) {
                rv[jj] = f2bf(usec ? cc : ss);
                float cn = cc * c1 - ss * s1; ss = ss * c1 + cc * s1; cc = cn;
            }
            uint4 pk;
            pk.x = (unsigned)rv[0] | ((unsigned)rv[1] << 16);
            pk.y = (unsigned)rv[2] | ((unsigned)rv[3] << 16);
            pk.z = (unsigned)rv[4] | ((unsigned)rv[5] << 16);
            pk.w = (unsigned)rv[6] | ((unsigned)rv[7] << 16);
            *(uint4*)&yrad[col * 40 + quad * 8] = pk;

            // ---- phi GEMM: phi(32 x 16e) = Wfold(32x32) @ rad(32 x 16e)
            bf16x8 brad = *(const bf16x8*)&yrad[col * 40 + quad * 8];
            float phi[2][4];
#pragma unroll
            for (int mt = 0; mt < 2; ++mt) {
                bf16x8 aw = *(const bf16x8*)&Wlds[OFF_WFOLD + (mt * 16 + col) * 40 + quad * 8];
                f32x4 pa = __builtin_amdgcn_mfma_f32_16x16x32_bf16(aw, brad, zero, 0, 0, 0);
#pragma unroll
                for (int r = 0; r < 4; ++r)
                    phi[mt][r] = valid ? (pa[r] + Bias[mt * 16 + quad * 4 + r]) : 0.f;
            }

            // ---- gather node features at dst (bf16 records)
            int nd = dst[eid];
            const unsigned short* rp = rec + (size_t)nd * 128;
            float la[2][4], lv[3][2][4];
#pragma unroll
            for (int mt = 0; mt < 2; ++mt) {
                ushort4 q = *(const ushort4*)&rp[mt * 16 + quad * 4];
                la[mt][0] = bf2f(q.x); la[mt][1] = bf2f(q.y); la[mt][2] = bf2f(q.z); la[mt][3] = bf2f(q.w);
#pragma unroll
                for (int i = 0; i < 3; ++i) {
                    ushort4 p = *(const ushort4*)&rp[32 + i * 32 + mt * 16 + quad * 4];
                    lv[i][mt][0] = bf2f(p.x); lv[i][mt][1] = bf2f(p.y); lv[i][mt][2] = bf2f(p.z); lv[i][mt][3] = bf2f(p.w);
                }
            }

            // ---- order-0 tensor products -> YA = [y000 | y110] (16e x 64k)
#pragma unroll
            for (int mt = 0; mt < 2; ++mt) {
                float y0[4], y1[4];
#pragma unroll
                for (int r = 0; r < 4; ++r) {
                    float dotv = lv[0][mt][r] * rh0 + lv[1][mt][r] * rh1 + lv[2][mt][r] * rh2;
                    y0[r] = la[mt][r] * phi[mt][r];
                    y1[r] = phi[mt][r] * dotv;
                }
                uint2 w0; w0.x = pack2(y0[0], y0[1]); w0.y = pack2(y0[2], y0[3]);
                *(uint2*)&ya[col * 72 + mt * 16 + quad * 4] = w0;
                uint2 w1; w1.x = pack2(y1[0], y1[1]); w1.y = pack2(y1[2], y1[3]);
                *(uint2*)&ya[col * 72 + 32 + mt * 16 + quad * 4] = w1;
            }

            // ---- psi_a = [y000|y110] @ [WY000|WY110].T   (64 out)
            f32x4 pacc[4] = {zero, zero, zero, zero};
#pragma unroll
            for (int ks = 0; ks < 2; ++ks) {
                bf16x8 bb = *(const bf16x8*)&ya[col * 72 + ks * 32 + quad * 8];
#pragma unroll
                for (int mt = 0; mt < 4; ++mt) {
                    bf16x8 aa = *(const bf16x8*)&Wlds[OFF_WCAT + (mt * 16 + col) * 72 + ks * 32 + quad * 8];
                    pacc[mt] = __builtin_amdgcn_mfma_f32_16x16x32_bf16(aa, bb, pacc[mt], 0, 0, 0);
                }
            }
            float psi[4][4];
#pragma unroll
            for (int mt = 0; mt < 4; ++mt)
#pragma unroll
                for (int r = 0; r < 4; ++r) psi[mt][r] = pacc[mt][r];

            // ---- t011 = y000 @ WY011.T (16 out, K=32)
            bf16x8 b0 = *(const bf16x8*)&ya[col * 72 + quad * 8];
            bf16x8 a011 = *(const bf16x8*)&Wlds[OFF_W011 + col * 40 + quad * 8];
            f32x4 t011v = __builtin_amdgcn_mfma_f32_16x16x32_bf16(a011, b0, zero, 0, 0, 0);

            // ---- psi_v per component: [y101_i|y111_i] @ [WY101|WY111].T + t011*rh_i
#pragma unroll
            for (int i = 0; i < 3; ++i) {
#pragma unroll
                for (int mt = 0; mt < 2; ++mt) {
                    float q1[4], q2[4];
#pragma unroll
                    for (int r = 0; r < 4; ++r) {
                        q1[r] = phi[mt][r] * lv[i][mt][r];
                        float cr;
                        if (i == 0)      cr = lv[1][mt][r] * rh2 - lv[2][mt][r] * rh1;
                        else if (i == 1) cr = lv[2][mt][r] * rh0 - lv[0][mt][r] * rh2;
                        else             cr = lv[0][mt][r] * rh1 - lv[1][mt][r] * rh0;
                        q2[r] = phi[mt][r] * cr;
                    }
                    uint2 wa; wa.x = pack2(q1[0], q1[1]); wa.y = pack2(q1[2], q1[3]);
                    *(uint2*)&yv[col * 72 + mt * 16 + quad * 4] = wa;
                    uint2 wb; wb.x = pack2(q2[0], q2[1]); wb.y = pack2(q2[2], q2[3]);
                    *(uint2*)&yv[col * 72 + 32 + mt * 16 + quad * 4] = wb;
                }
                f32x4 vacc = zero;
#pragma unroll
                for (int ks = 0; ks < 2; ++ks) {
                    bf16x8 bb = *(const bf16x8*)&yv[col * 72 + ks * 32 + quad * 8];
                    bf16x8 aa = *(const bf16x8*)&Wlds[OFF_WV + col * 72 + ks * 32 + quad * 8];
                    vacc = __builtin_amdgcn_mfma_f32_16x16x32_bf16(aa, bb, vacc, 0, 0, 0);
                }
                float rhi = (i == 0) ? rh0 : (i == 1) ? rh1 : rh2;
#pragma unroll
                for (int r = 0; r < 4; ++r) {
                    float val = 0.1f * (vacc[r] + t011v[r] * rhi);
                    accV[r * 3 + i] += valid ? val : 0.f;
                }
            }

            // ---- residual MLP on psi_a (3x 64x64 GEMM, leaky_relu 0.1)
#pragma unroll
            for (int mt = 0; mt < 4; ++mt) {
                uint2 w; w.x = pack2(psi[mt][0], psi[mt][1]); w.y = pack2(psi[mt][2], psi[mt][3]);
                *(uint2*)&hb[col * 72 + mt * 16 + quad * 4] = w;
            }
            // layer 1
            f32x4 hacc[4] = {zero, zero, zero, zero};
#pragma unroll
            for (int ks = 0; ks < 2; ++ks) {
                bf16x8 bb = *(const bf16x8*)&hb[col * 72 + ks * 32 + quad * 8];
#pragma unroll
                for (int mt = 0; mt < 4; ++mt) {
                    bf16x8 aa = *(const bf16x8*)&Wlds[OFF_WM1 + (mt * 16 + col) * 72 + ks * 32 + quad * 8];
                    hacc[mt] = __builtin_amdgcn_mfma_f32_16x16x32_bf16(aa, bb, hacc[mt], 0, 0, 0);
                }
            }
#pragma unroll
            for (int mt = 0; mt < 4; ++mt) {
                float h[4];
#pragma unroll
                for (int r = 0; r < 4; ++r) {
                    float x = hacc[mt][r] + Bias[32 + mt * 16 + quad * 4 + r];
                    h[r] = fmaxf(x, 0.1f * x);
                }
                uint2 w; w.x = pack2(h[0], h[1]); w.y = pack2(h[2], h[3]);
                *(uint2*)&hb[col * 72 + mt * 16 + quad * 4] = w;
            }
            // layer 2
            f32x4 gacc[4] = {zero, zero, zero, zero};
#pragma unroll
            for (int ks = 0; ks < 2; ++ks) {
                bf16x8 bb = *(const bf16x8*)&hb[col * 72 + ks * 32 + quad * 8];
#pragma unroll
                for (int mt = 0; mt < 4; ++mt) {
                    bf16x8 aa = *(const bf16x8*)&Wlds[OFF_WM2 + (mt * 16 + col) * 72 + ks * 32 + quad * 8];
                    gacc[mt] = __builtin_amdgcn_mfma_f32_16x16x32_bf16(aa, bb, gacc[mt], 0, 0, 0);
                }
            }
#pragma unroll
            for (int mt = 0; mt < 4; ++mt) {
                float h[4];
#pragma unroll
                for (int r = 0; r < 4; ++r) {
                    float x = gacc[mt][r] + Bias[96 + mt * 16 + quad * 4 + r];
                    h[r] = fmaxf(x, 0.1f * x);
                }
                uint2 w; w.x = pack2(h[0], h[1]); w.y = pack2(h[2], h[3]);
                *(uint2*)&hb[col * 72 + mt * 16 + quad * 4] = w;
            }
            // layer 3 (no bias) + residual + scale + accumulate (masked)
            f32x4 oacc[4] = {zero, zero, zero, zero};
#pragma unroll
            for (int ks = 0; ks < 2; ++ks) {
                bf16x8 bb = *(const bf16x8*)&hb[col * 72 + ks * 32 + quad * 8];
#pragma unroll
                for (int mt = 0; mt < 4; ++mt) {
                    bf16x8 aa = *(const bf16x8*)&Wlds[OFF_WM3 + (mt * 16 + col) * 72 + ks * 32 + quad * 8];
                    oacc[mt] = __builtin_amdgcn_mfma_f32_16x16x32_bf16(aa, bb, oacc[mt], 0, 0, 0);
                }
            }
#pragma unroll
            for (int mt = 0; mt < 4; ++mt)
#pragma unroll
                for (int r = 0; r < 4; ++r) {
                    float val = 0.1f * (psi[mt][r] + oacc[mt][r]);
                    accA[mt][r] += valid ? val : 0.f;
                }
        }

        // ---- butterfly reduction across the 16 cols (lanes quad*16 + col)
#pragma unroll
        for (int d2 = 1; d2 < 16; d2 <<= 1) {
#pragma unroll
            for (int mt = 0; mt < 4; ++mt)
#pragma unroll
                for (int r = 0; r < 4; ++r) accA[mt][r] += __shfl_xor(accA[mt][r], d2);
#pragma unroll
            for (int j = 0; j < 12; ++j) accV[j] += __shfl_xor(accV[j], d2);
        }

        // ---- store (col 0 lanes: one per quad)
        if (col == 0) {
#pragma unroll
            for (int mt = 0; mt < 4; ++mt) {
                float4 st = {accA[mt][0], accA[mt][1], accA[mt][2], accA[mt][3]};
                *(float4*)&outA[(size_t)n * 64 + mt * 16 + quad * 4] = st;
            }
#pragma unroll
            for (int j = 0; j < 3; ++j) {
                float4 st = {accV[j * 4 + 0], accV[j * 4 + 1], accV[j * 4 + 2], accV[j * 4 + 3]};
                *(float4*)&outV[(size_t)n * 48 + quad * 12 + j * 4] = st;
            }
        }
    }
}

extern "C" void kernel_launch(void* const* d_in, const int* in_sizes, int n_in,
                              void* d_out, int out_size, void* d_ws, size_t ws_size,
                              hipStream_t stream) {
    const float* r_ij  = (const float*)d_in[0];
    const float* x_a   = (const float*)d_in[1];
    const float* x_v   = (const float*)d_in[2];
    const int*   src   = (const int*)d_in[3];
    const int*   dst   = (const int*)d_in[4];
    const float* W_L0  = (const float*)d_in[5];
    const float* W_L1  = (const float*)d_in[6];
    const float* W_enc = (const float*)d_in[7];
    const float* b_enc = (const float*)d_in[8];
    const float* WY000 = (const float*)d_in[9];
    const float* WY110 = (const float*)d_in[10];
    const float* WY011 = (const float*)d_in[11];
    const float* WY101 = (const float*)d_in[12];
    const float* WY111 = (const float*)d_in[13];
    const float* Wm1   = (const float*)d_in[14];
    const float* bm1   = (const float*)d_in[15];
    const float* Wm2   = (const float*)d_in[16];
    const float* bm2   = (const float*)d_in[17];
    const float* Wm3   = (const float*)d_in[18];
    float* out = (float*)d_out;

    char* ws = (char*)d_ws;
    unsigned short* rec = (unsigned short*)(ws + REC_OFF);
    int* cnt            = (int*)(ws + CNT_OFF);
    int* ell            = (int*)(ws + ELL_OFF);

    hipMemsetAsync(d_out, 0, (size_t)out_size * sizeof(float), stream);
    hipMemsetAsync(cnt, 0, N_NODES * sizeof(int), stream);

    node_kernel<<<(N_NODES * 32) / 256, 256, 0, stream>>>(x_a, x_v, W_L0, W_L1, rec);
    ell_kernel<<<(N_EDGES + 255) / 256, 256, 0, stream>>>(src, cnt, ell);
    node_major_kernel<<<2048, 256, 0, stream>>>(r_ij, dst, W_enc, b_enc,
            WY000, WY110, WY011, WY101, WY111, Wm1, bm1, Wm2, bm2, Wm3,
            rec, cnt, ell, out);
}